// Round 11
// baseline (186.054 us; speedup 1.0000x reference)
//
#include <hip/hip_runtime.h>

#define D    128
#define NT   256
#define CSH  4        // counts stride shift: 16 ints = one 64-B line per node

typedef __attribute__((ext_vector_type(4))) _Float16 half4;
typedef __attribute__((ext_vector_type(4))) float    f32x4;

__device__ __forceinline__ float4 elu_mul(float4 g, float4 w) {
    float4 v;
    v.x = g.x * w.x; v.y = g.y * w.y; v.z = g.z * w.z; v.w = g.w * w.w;
    v.x = (v.x > 0.0f) ? v.x : (__expf(v.x) - 1.0f);
    v.y = (v.y > 0.0f) ? v.y : (__expf(v.y) - 1.0f);
    v.z = (v.z > 0.0f) ? v.z : (__expf(v.z) - 1.0f);
    v.w = (v.w > 0.0f) ? v.w : (__expf(v.w) - 1.0f);
    return v;
}

// ---------------------------------------------------------------------------
// K1: emb = elu(ge*w) fp16 (one quad/thread) + zero padded counts.
// ---------------------------------------------------------------------------
__global__ __launch_bounds__(NT)
void emb_kernel(const float* __restrict__ ge, const float* __restrict__ weight,
                _Float16* __restrict__ emb, int* __restrict__ counts, int n_nodes) {
    int t = blockIdx.x * NT + threadIdx.x;
    int quads = n_nodes * (D / 4);

    int nctr = n_nodes << CSH;
    if (t < nctr) counts[t] = 0;

    if (t < quads) {
        int col = (t & 31) * 4;  // 32 quads per row
        float4 g = *reinterpret_cast<const float4*>(ge + (size_t)t * 4);
        float4 w = *reinterpret_cast<const float4*>(weight + col);
        float4 v = elu_mul(g, w);
        half4 h;
        h.x = (_Float16)v.x; h.y = (_Float16)v.y;
        h.z = (_Float16)v.z; h.w = (_Float16)v.w;
        *reinterpret_cast<half4*>(emb + (size_t)t * 4) = h;
    }
}

// ---------------------------------------------------------------------------
// K2: histogram with returned rank (rank store coalesced).
// ---------------------------------------------------------------------------
__global__ __launch_bounds__(NT)
void hist_rank_kernel(const int* __restrict__ dst, int* __restrict__ counts,
                      int* __restrict__ rank, int n_edges) {
    int i = blockIdx.x * NT + threadIdx.x;
    if (i < n_edges) rank[i] = atomicAdd(&counts[dst[i] << CSH], 1);
}

// ---------------------------------------------------------------------------
// K3: exclusive scan of counts -> offsets, ONE block of 1024 threads.
//     Each thread serially scans its chunk; Hillis-Steele over 1024 partials.
// ---------------------------------------------------------------------------
__global__ __launch_bounds__(1024)
void scan_kernel(const int* __restrict__ counts, int* __restrict__ offsets,
                 int n_nodes, int n_edges) {
    __shared__ int part[1024];
    int t = threadIdx.x;
    int items = (n_nodes + 1023) >> 10;
    int beg = t * items;
    int end = beg + items; if (end > n_nodes) end = n_nodes;
    if (beg > n_nodes) beg = n_nodes;

    int sum = 0;
    for (int i = beg; i < end; ++i) sum += counts[i << CSH];
    part[t] = sum;
    __syncthreads();
    for (int d = 1; d < 1024; d <<= 1) {
        int x = (t >= d) ? part[t - d] : 0;
        __syncthreads();
        part[t] += x;
        __syncthreads();
    }
    int run = (t > 0) ? part[t - 1] : 0;  // exclusive prefix of my chunk
    for (int i = beg; i < end; ++i) {
        offsets[i] = run;
        run += counts[i << CSH];
    }
    if (t == 1023) offsets[n_nodes] = n_edges;  // all dst < n_nodes -> total == E
}

// ---------------------------------------------------------------------------
// K4: tight bucket fill — bucket[offsets[dst] + rank] = record. No atomics,
//     no overflow possible (exact CSR).
// ---------------------------------------------------------------------------
__global__ __launch_bounds__(NT)
void fill_kernel(const int* __restrict__ e_feat, const int* __restrict__ src,
                 const int* __restrict__ dst, const int* __restrict__ rank,
                 const int* __restrict__ offsets,
                 unsigned int* __restrict__ bucket, int n_edges) {
    int i = blockIdx.x * NT + threadIdx.x;
    if (i >= n_edges) return;
    int ef = e_feat[i];
    unsigned int flag = (ef == 0 || ef == 6 || ef == 14 || ef == 30) ? 1u : 0u;
    unsigned int rec  = (unsigned int)src[i] | (flag << 31);
    bucket[offsets[dst[i]] + rank[i]] = rec;
}

// ---------------------------------------------------------------------------
// K5: gather. 32 lanes/node, 4 fp16 cols/lane; 8/4/1 unrolled record loop
//     (records broadcast-loaded; rows are the real traffic). NT store to out.
// ---------------------------------------------------------------------------
__global__ __launch_bounds__(NT)
void gather_kernel(const _Float16* __restrict__ emb,
                   const int* __restrict__ offsets,
                   const unsigned int* __restrict__ bucket,
                   float* __restrict__ out, int n_nodes) {
    int tid = blockIdx.x * NT + threadIdx.x;
    int node = tid >> 5;
    if (node >= n_nodes) return;
    int col = (tid & 31) * 4;

    int beg = offsets[node];
    int end = offsets[node + 1];
    float4 acc = make_float4(0.f, 0.f, 0.f, 0.f);

    int i = beg;
    for (; i + 8 <= end; i += 8) {
        unsigned int r0 = bucket[i+0], r1 = bucket[i+1], r2 = bucket[i+2], r3 = bucket[i+3];
        unsigned int r4 = bucket[i+4], r5 = bucket[i+5], r6 = bucket[i+6], r7 = bucket[i+7];
        half4 h0 = *reinterpret_cast<const half4*>(emb + (size_t)(r0 & 0x7FFFFFFFu) * D + col);
        half4 h1 = *reinterpret_cast<const half4*>(emb + (size_t)(r1 & 0x7FFFFFFFu) * D + col);
        half4 h2 = *reinterpret_cast<const half4*>(emb + (size_t)(r2 & 0x7FFFFFFFu) * D + col);
        half4 h3 = *reinterpret_cast<const half4*>(emb + (size_t)(r3 & 0x7FFFFFFFu) * D + col);
        half4 h4 = *reinterpret_cast<const half4*>(emb + (size_t)(r4 & 0x7FFFFFFFu) * D + col);
        half4 h5 = *reinterpret_cast<const half4*>(emb + (size_t)(r5 & 0x7FFFFFFFu) * D + col);
        half4 h6 = *reinterpret_cast<const half4*>(emb + (size_t)(r6 & 0x7FFFFFFFu) * D + col);
        half4 h7 = *reinterpret_cast<const half4*>(emb + (size_t)(r7 & 0x7FFFFFFFu) * D + col);
        float m0 = (r0 >> 31) ? 2.f : 1.f, m1 = (r1 >> 31) ? 2.f : 1.f;
        float m2 = (r2 >> 31) ? 2.f : 1.f, m3 = (r3 >> 31) ? 2.f : 1.f;
        float m4 = (r4 >> 31) ? 2.f : 1.f, m5 = (r5 >> 31) ? 2.f : 1.f;
        float m6 = (r6 >> 31) ? 2.f : 1.f, m7 = (r7 >> 31) ? 2.f : 1.f;
        acc.x += (float)h0.x*m0 + (float)h1.x*m1 + (float)h2.x*m2 + (float)h3.x*m3
               + (float)h4.x*m4 + (float)h5.x*m5 + (float)h6.x*m6 + (float)h7.x*m7;
        acc.y += (float)h0.y*m0 + (float)h1.y*m1 + (float)h2.y*m2 + (float)h3.y*m3
               + (float)h4.y*m4 + (float)h5.y*m5 + (float)h6.y*m6 + (float)h7.y*m7;
        acc.z += (float)h0.z*m0 + (float)h1.z*m1 + (float)h2.z*m2 + (float)h3.z*m3
               + (float)h4.z*m4 + (float)h5.z*m5 + (float)h6.z*m6 + (float)h7.z*m7;
        acc.w += (float)h0.w*m0 + (float)h1.w*m1 + (float)h2.w*m2 + (float)h3.w*m3
               + (float)h4.w*m4 + (float)h5.w*m5 + (float)h6.w*m6 + (float)h7.w*m7;
    }
    for (; i + 4 <= end; i += 4) {
        unsigned int r0 = bucket[i+0], r1 = bucket[i+1], r2 = bucket[i+2], r3 = bucket[i+3];
        half4 h0 = *reinterpret_cast<const half4*>(emb + (size_t)(r0 & 0x7FFFFFFFu) * D + col);
        half4 h1 = *reinterpret_cast<const half4*>(emb + (size_t)(r1 & 0x7FFFFFFFu) * D + col);
        half4 h2 = *reinterpret_cast<const half4*>(emb + (size_t)(r2 & 0x7FFFFFFFu) * D + col);
        half4 h3 = *reinterpret_cast<const half4*>(emb + (size_t)(r3 & 0x7FFFFFFFu) * D + col);
        float m0 = (r0 >> 31) ? 2.f : 1.f, m1 = (r1 >> 31) ? 2.f : 1.f;
        float m2 = (r2 >> 31) ? 2.f : 1.f, m3 = (r3 >> 31) ? 2.f : 1.f;
        acc.x += (float)h0.x*m0 + (float)h1.x*m1 + (float)h2.x*m2 + (float)h3.x*m3;
        acc.y += (float)h0.y*m0 + (float)h1.y*m1 + (float)h2.y*m2 + (float)h3.y*m3;
        acc.z += (float)h0.z*m0 + (float)h1.z*m1 + (float)h2.z*m2 + (float)h3.z*m3;
        acc.w += (float)h0.w*m0 + (float)h1.w*m1 + (float)h2.w*m2 + (float)h3.w*m3;
    }
    for (; i < end; ++i) {
        unsigned int r = bucket[i];
        half4 h = *reinterpret_cast<const half4*>(emb + (size_t)(r & 0x7FFFFFFFu) * D + col);
        float m = (r >> 31) ? 2.f : 1.f;
        acc.x += (float)h.x*m; acc.y += (float)h.y*m;
        acc.z += (float)h.z*m; acc.w += (float)h.w*m;
    }

    f32x4 o;
    o.x = acc.x; o.y = acc.y; o.z = acc.z; o.w = acc.w;
    __builtin_nontemporal_store(o, reinterpret_cast<f32x4*>(out + (size_t)node * D + col));
}

// ---------------------------------------------------------------------------
// Fallback (tiny workspace): atomic scatter.
// ---------------------------------------------------------------------------
__global__ void edge_scatter_fallback(const float* __restrict__ ge,
                                      const float* __restrict__ weight,
                                      const int* __restrict__ e_feat,
                                      const int* __restrict__ src,
                                      const int* __restrict__ dst,
                                      float* __restrict__ out, int n_edges) {
    long long tid = (long long)blockIdx.x * blockDim.x + threadIdx.x;
    int edge = (int)(tid >> 5);
    if (edge >= n_edges) return;
    int col = (int)(tid & 31) * 4;
    int e = e_feat[edge];
    float mult = (e == 0 || e == 6 || e == 14 || e == 30) ? 2.0f : 1.0f;
    float4 w = *reinterpret_cast<const float4*>(weight + col);
    float4 g = *reinterpret_cast<const float4*>(ge + (long long)src[edge] * D + col);
    float4 v = elu_mul(g, w);
    float* o = out + (long long)dst[edge] * D + col;
    atomicAdd(o + 0, v.x * mult);
    atomicAdd(o + 1, v.y * mult);
    atomicAdd(o + 2, v.z * mult);
    atomicAdd(o + 3, v.w * mult);
}

extern "C" void kernel_launch(void* const* d_in, const int* in_sizes, int n_in,
                              void* d_out, int out_size, void* d_ws, size_t ws_size,
                              hipStream_t stream) {
    const float* ge     = (const float*)d_in[0];   // [N, 128]
    const float* weight = (const float*)d_in[1];   // [1, 128]
    const int*   e_feat = (const int*)d_in[2];     // [E]
    const int*   src    = (const int*)d_in[3];     // [E]
    const int*   dst    = (const int*)d_in[4];     // [E]
    float* out = (float*)d_out;                    // [N, 128]

    int n_edges = in_sizes[2];
    int n_nodes = out_size / D;

    // Workspace: emb | counts (padded 64 B/node) | rank | offsets | bucket
    auto align256 = [](size_t x) { return (x + 255) & ~(size_t)255; };
    size_t o_emb    = 0;
    size_t o_counts = o_emb    + align256((size_t)n_nodes * D * sizeof(_Float16));
    size_t o_rank   = o_counts + align256((size_t)n_nodes * 64);
    size_t o_offs   = o_rank   + align256((size_t)n_edges * 4);
    size_t o_bucket = o_offs   + align256((size_t)(n_nodes + 1) * 4);
    size_t need     = o_bucket + align256((size_t)n_edges * 4);

    if (ws_size < need) {
        (void)hipMemsetAsync(d_out, 0, (size_t)out_size * sizeof(float), stream);
        long long total = (long long)n_edges * 32;
        edge_scatter_fallback<<<(int)((total + 255) / 256), 256, 0, stream>>>(
            ge, weight, e_feat, src, dst, out, n_edges);
        return;
    }

    char* ws = (char*)d_ws;
    _Float16*     emb     = (_Float16*)(ws + o_emb);
    int*          counts  = (int*)(ws + o_counts);
    int*          rank    = (int*)(ws + o_rank);
    int*          offsets = (int*)(ws + o_offs);
    unsigned int* bucket  = (unsigned int*)(ws + o_bucket);

    int quads = n_nodes * (D / 4);
    int k1_threads = quads > (n_nodes << CSH) ? quads : (n_nodes << CSH);
    int k1b = (k1_threads + NT - 1) / NT;
    int eb  = (n_edges + NT - 1) / NT;

    emb_kernel<<<k1b, NT, 0, stream>>>(ge, weight, emb, counts, n_nodes);
    hist_rank_kernel<<<eb, NT, 0, stream>>>(dst, counts, rank, n_edges);
    scan_kernel<<<1, 1024, 0, stream>>>(counts, offsets, n_nodes, n_edges);
    fill_kernel<<<eb, NT, 0, stream>>>(e_feat, src, dst, rank, offsets, bucket, n_edges);

    long long total = (long long)n_nodes * 32;
    gather_kernel<<<(int)((total + 255) / 256), NT, 0, stream>>>(
        emb, offsets, bucket, out, n_nodes);
}

// Round 13
// 82.366 us; speedup vs baseline: 2.2589x; 2.2589x over previous
//
#include <hip/hip_runtime.h>

#define D    128
#define NT   256

typedef __attribute__((ext_vector_type(4))) _Float16 half4;
typedef __attribute__((ext_vector_type(4))) float    f32x4;

__device__ __forceinline__ float4 elu_mul(float4 g, float4 w) {
    float4 v;
    v.x = g.x * w.x; v.y = g.y * w.y; v.z = g.z * w.z; v.w = g.w * w.w;
    v.x = (v.x > 0.0f) ? v.x : (__expf(v.x) - 1.0f);
    v.y = (v.y > 0.0f) ? v.y : (__expf(v.y) - 1.0f);
    v.z = (v.z > 0.0f) ? v.z : (__expf(v.z) - 1.0f);
    v.w = (v.w > 0.0f) ? v.w : (__expf(v.w) - 1.0f);
    return v;
}

// ---------------------------------------------------------------------------
// K1: emb = elu(ge*w) fp16 (one quad/thread) + zero counts (dense).
// ---------------------------------------------------------------------------
__global__ __launch_bounds__(NT)
void emb_kernel(const float* __restrict__ ge, const float* __restrict__ weight,
                _Float16* __restrict__ emb, int* __restrict__ counts, int n_nodes) {
    int t = blockIdx.x * NT + threadIdx.x;
    int quads = n_nodes * (D / 4);

    if (t < n_nodes) counts[t] = 0;

    if (t < quads) {
        int col = (t & 31) * 4;  // 32 quads per row
        float4 g = *reinterpret_cast<const float4*>(ge + (size_t)t * 4);
        float4 w = *reinterpret_cast<const float4*>(weight + col);
        float4 v = elu_mul(g, w);
        half4 h;
        h.x = (_Float16)v.x; h.y = (_Float16)v.y;
        h.z = (_Float16)v.z; h.w = (_Float16)v.w;
        *reinterpret_cast<half4*>(emb + (size_t)t * 4) = h;
    }
}

// ---------------------------------------------------------------------------
// K2: histogram with returned rank (rank store coalesced).
// ---------------------------------------------------------------------------
__global__ __launch_bounds__(NT)
void hist_rank_kernel(const int* __restrict__ dst, int* __restrict__ counts,
                      int* __restrict__ rank, int n_edges) {
    int i = blockIdx.x * NT + threadIdx.x;
    if (i < n_edges) rank[i] = atomicAdd(&counts[dst[i]], 1);
}

// ---------------------------------------------------------------------------
// K3a: per-chunk (256) exclusive scan of counts -> offsets; chunk totals.
//      idx == n_nodes (when inside the tail chunk) gets the scanned value,
//      which is the chunk-local exclusive prefix over the real tail nodes.
// ---------------------------------------------------------------------------
__global__ __launch_bounds__(NT)
void scan1_kernel(const int* __restrict__ counts, int* __restrict__ offsets,
                  int* __restrict__ bsum, int n_nodes) {
    __shared__ int s[NT];
    int t = threadIdx.x;
    int idx = blockIdx.x * NT + t;
    int v = (idx < n_nodes) ? counts[idx] : 0;
    s[t] = v;
    __syncthreads();
    for (int d = 1; d < NT; d <<= 1) {
        int x = (t >= d) ? s[t - d] : 0;
        __syncthreads();
        s[t] += x;
        __syncthreads();
    }
    if (idx <= n_nodes) offsets[idx] = s[t] - v;  // chunk-local exclusive
    if (t == NT - 1) bsum[blockIdx.x] = s[t];     // chunk total
}

// ---------------------------------------------------------------------------
// K3b: exclusive scan of chunk totals in place; bsum[nchunks] = grand total.
//      If n_nodes is chunk-aligned, index n_nodes was outside scan1's grid ->
//      zero it here (its chunk-local prefix in the nonexistent chunk is 0).
// ---------------------------------------------------------------------------
__global__ __launch_bounds__(NT)
void scan2_kernel(int* __restrict__ bsum, int* __restrict__ offsets,
                  int nchunks, int n_nodes) {
    __shared__ int s[NT];
    int t = threadIdx.x;
    int v = (t < nchunks) ? bsum[t] : 0;
    s[t] = v;
    __syncthreads();
    for (int d = 1; d < NT; d <<= 1) {
        int x = (t >= d) ? s[t - d] : 0;
        __syncthreads();
        s[t] += x;
        __syncthreads();
    }
    if (t < nchunks) bsum[t] = s[t] - v;                 // exclusive
    if (t == nchunks - 1) bsum[nchunks] = s[t];          // total == n_edges
    if (t == 0 && (n_nodes & (NT - 1)) == 0) offsets[n_nodes] = 0;
}

// ---------------------------------------------------------------------------
// K4: tight bucket fill — bucket[offsets[d] + bsum[d>>8] + rank] = record.
// ---------------------------------------------------------------------------
__global__ __launch_bounds__(NT)
void fill_kernel(const int* __restrict__ e_feat, const int* __restrict__ src,
                 const int* __restrict__ dst, const int* __restrict__ rank,
                 const int* __restrict__ offsets, const int* __restrict__ bsum,
                 unsigned int* __restrict__ bucket, int n_edges) {
    int i = blockIdx.x * NT + threadIdx.x;
    if (i >= n_edges) return;
    int ef = e_feat[i];
    unsigned int flag = (ef == 0 || ef == 6 || ef == 14 || ef == 30) ? 1u : 0u;
    unsigned int rec  = (unsigned int)src[i] | (flag << 31);
    int d = dst[i];
    bucket[offsets[d] + bsum[d >> 8] + rank[i]] = rec;
}

// ---------------------------------------------------------------------------
// K5: gather. 32 lanes/node, 4 fp16 cols/lane; 8/4/1 unrolled record loop.
// ---------------------------------------------------------------------------
__global__ __launch_bounds__(NT)
void gather_kernel(const _Float16* __restrict__ emb,
                   const int* __restrict__ offsets, const int* __restrict__ bsum,
                   const unsigned int* __restrict__ bucket,
                   float* __restrict__ out, int n_nodes) {
    int tid = blockIdx.x * NT + threadIdx.x;
    int node = tid >> 5;
    if (node >= n_nodes) return;
    int col = (tid & 31) * 4;

    int beg = offsets[node] + bsum[node >> 8];
    int end = offsets[node + 1] + bsum[(node + 1) >> 8];
    float4 acc = make_float4(0.f, 0.f, 0.f, 0.f);

    int i = beg;
    for (; i + 8 <= end; i += 8) {
        unsigned int r0 = bucket[i+0], r1 = bucket[i+1], r2 = bucket[i+2], r3 = bucket[i+3];
        unsigned int r4 = bucket[i+4], r5 = bucket[i+5], r6 = bucket[i+6], r7 = bucket[i+7];
        half4 h0 = *reinterpret_cast<const half4*>(emb + (size_t)(r0 & 0x7FFFFFFFu) * D + col);
        half4 h1 = *reinterpret_cast<const half4*>(emb + (size_t)(r1 & 0x7FFFFFFFu) * D + col);
        half4 h2 = *reinterpret_cast<const half4*>(emb + (size_t)(r2 & 0x7FFFFFFFu) * D + col);
        half4 h3 = *reinterpret_cast<const half4*>(emb + (size_t)(r3 & 0x7FFFFFFFu) * D + col);
        half4 h4 = *reinterpret_cast<const half4*>(emb + (size_t)(r4 & 0x7FFFFFFFu) * D + col);
        half4 h5 = *reinterpret_cast<const half4*>(emb + (size_t)(r5 & 0x7FFFFFFFu) * D + col);
        half4 h6 = *reinterpret_cast<const half4*>(emb + (size_t)(r6 & 0x7FFFFFFFu) * D + col);
        half4 h7 = *reinterpret_cast<const half4*>(emb + (size_t)(r7 & 0x7FFFFFFFu) * D + col);
        float m0 = (r0 >> 31) ? 2.f : 1.f, m1 = (r1 >> 31) ? 2.f : 1.f;
        float m2 = (r2 >> 31) ? 2.f : 1.f, m3 = (r3 >> 31) ? 2.f : 1.f;
        float m4 = (r4 >> 31) ? 2.f : 1.f, m5 = (r5 >> 31) ? 2.f : 1.f;
        float m6 = (r6 >> 31) ? 2.f : 1.f, m7 = (r7 >> 31) ? 2.f : 1.f;
        acc.x += (float)h0.x*m0 + (float)h1.x*m1 + (float)h2.x*m2 + (float)h3.x*m3
               + (float)h4.x*m4 + (float)h5.x*m5 + (float)h6.x*m6 + (float)h7.x*m7;
        acc.y += (float)h0.y*m0 + (float)h1.y*m1 + (float)h2.y*m2 + (float)h3.y*m3
               + (float)h4.y*m4 + (float)h5.y*m5 + (float)h6.y*m6 + (float)h7.y*m7;
        acc.z += (float)h0.z*m0 + (float)h1.z*m1 + (float)h2.z*m2 + (float)h3.z*m3
               + (float)h4.z*m4 + (float)h5.z*m5 + (float)h6.z*m6 + (float)h7.z*m7;
        acc.w += (float)h0.w*m0 + (float)h1.w*m1 + (float)h2.w*m2 + (float)h3.w*m3
               + (float)h4.w*m4 + (float)h5.w*m5 + (float)h6.w*m6 + (float)h7.w*m7;
    }
    for (; i + 4 <= end; i += 4) {
        unsigned int r0 = bucket[i+0], r1 = bucket[i+1], r2 = bucket[i+2], r3 = bucket[i+3];
        half4 h0 = *reinterpret_cast<const half4*>(emb + (size_t)(r0 & 0x7FFFFFFFu) * D + col);
        half4 h1 = *reinterpret_cast<const half4*>(emb + (size_t)(r1 & 0x7FFFFFFFu) * D + col);
        half4 h2 = *reinterpret_cast<const half4*>(emb + (size_t)(r2 & 0x7FFFFFFFu) * D + col);
        half4 h3 = *reinterpret_cast<const half4*>(emb + (size_t)(r3 & 0x7FFFFFFFu) * D + col);
        float m0 = (r0 >> 31) ? 2.f : 1.f, m1 = (r1 >> 31) ? 2.f : 1.f;
        float m2 = (r2 >> 31) ? 2.f : 1.f, m3 = (r3 >> 31) ? 2.f : 1.f;
        acc.x += (float)h0.x*m0 + (float)h1.x*m1 + (float)h2.x*m2 + (float)h3.x*m3;
        acc.y += (float)h0.y*m0 + (float)h1.y*m1 + (float)h2.y*m2 + (float)h3.y*m3;
        acc.z += (float)h0.z*m0 + (float)h1.z*m1 + (float)h2.z*m2 + (float)h3.z*m3;
        acc.w += (float)h0.w*m0 + (float)h1.w*m1 + (float)h2.w*m2 + (float)h3.w*m3;
    }
    for (; i < end; ++i) {
        unsigned int r = bucket[i];
        half4 h = *reinterpret_cast<const half4*>(emb + (size_t)(r & 0x7FFFFFFFu) * D + col);
        float m = (r >> 31) ? 2.f : 1.f;
        acc.x += (float)h.x*m; acc.y += (float)h.y*m;
        acc.z += (float)h.z*m; acc.w += (float)h.w*m;
    }

    f32x4 o;
    o.x = acc.x; o.y = acc.y; o.z = acc.z; o.w = acc.w;
    __builtin_nontemporal_store(o, reinterpret_cast<f32x4*>(out + (size_t)node * D + col));
}

// ---------------------------------------------------------------------------
// Fallback (tiny workspace or huge node count): atomic scatter.
// ---------------------------------------------------------------------------
__global__ void edge_scatter_fallback(const float* __restrict__ ge,
                                      const float* __restrict__ weight,
                                      const int* __restrict__ e_feat,
                                      const int* __restrict__ src,
                                      const int* __restrict__ dst,
                                      float* __restrict__ out, int n_edges) {
    long long tid = (long long)blockIdx.x * blockDim.x + threadIdx.x;
    int edge = (int)(tid >> 5);
    if (edge >= n_edges) return;
    int col = (int)(tid & 31) * 4;
    int e = e_feat[edge];
    float mult = (e == 0 || e == 6 || e == 14 || e == 30) ? 2.0f : 1.0f;
    float4 w = *reinterpret_cast<const float4*>(weight + col);
    float4 g = *reinterpret_cast<const float4*>(ge + (long long)src[edge] * D + col);
    float4 v = elu_mul(g, w);
    float* o = out + (long long)dst[edge] * D + col;
    atomicAdd(o + 0, v.x * mult);
    atomicAdd(o + 1, v.y * mult);
    atomicAdd(o + 2, v.z * mult);
    atomicAdd(o + 3, v.w * mult);
}

extern "C" void kernel_launch(void* const* d_in, const int* in_sizes, int n_in,
                              void* d_out, int out_size, void* d_ws, size_t ws_size,
                              hipStream_t stream) {
    const float* ge     = (const float*)d_in[0];   // [N, 128]
    const float* weight = (const float*)d_in[1];   // [1, 128]
    const int*   e_feat = (const int*)d_in[2];     // [E]
    const int*   src    = (const int*)d_in[3];     // [E]
    const int*   dst    = (const int*)d_in[4];     // [E]
    float* out = (float*)d_out;                    // [N, 128]

    int n_edges = in_sizes[2];
    int n_nodes = out_size / D;

    // Workspace: emb | counts | offsets | bsum | rank | bucket
    auto align256 = [](size_t x) { return (x + 255) & ~(size_t)255; };
    size_t o_emb    = 0;
    size_t o_counts = o_emb    + align256((size_t)n_nodes * D * sizeof(_Float16));
    size_t o_offs   = o_counts + align256((size_t)n_nodes * 4);
    size_t o_bsum   = o_offs   + align256((size_t)(n_nodes + 1) * 4);
    size_t o_rank   = o_bsum   + align256(260 * 4);
    size_t o_bucket = o_rank   + align256((size_t)n_edges * 4);
    size_t need     = o_bucket + align256((size_t)n_edges * 4);

    int nchunks = (n_nodes + NT - 1) / NT;  // 196 for N=50000

    if (ws_size < need || nchunks > NT) {
        (void)hipMemsetAsync(d_out, 0, (size_t)out_size * sizeof(float), stream);
        long long total = (long long)n_edges * 32;
        edge_scatter_fallback<<<(int)((total + 255) / 256), 256, 0, stream>>>(
            ge, weight, e_feat, src, dst, out, n_edges);
        return;
    }

    char* ws = (char*)d_ws;
    _Float16*     emb     = (_Float16*)(ws + o_emb);
    int*          counts  = (int*)(ws + o_counts);
    int*          offsets = (int*)(ws + o_offs);
    int*          bsum    = (int*)(ws + o_bsum);
    int*          rank    = (int*)(ws + o_rank);
    unsigned int* bucket  = (unsigned int*)(ws + o_bucket);

    int quads = n_nodes * (D / 4);
    int k1b = (quads + NT - 1) / NT;           // quads >= n_nodes, covers both
    int eb  = (n_edges + NT - 1) / NT;

    emb_kernel<<<k1b, NT, 0, stream>>>(ge, weight, emb, counts, n_nodes);
    hist_rank_kernel<<<eb, NT, 0, stream>>>(dst, counts, rank, n_edges);
    scan1_kernel<<<nchunks, NT, 0, stream>>>(counts, offsets, bsum, n_nodes);
    scan2_kernel<<<1, NT, 0, stream>>>(bsum, offsets, nchunks, n_nodes);
    fill_kernel<<<eb, NT, 0, stream>>>(e_feat, src, dst, rank, offsets, bsum,
                                       bucket, n_edges);

    long long total = (long long)n_nodes * 32;
    gather_kernel<<<(int)((total + 255) / 256), NT, 0, stream>>>(
        emb, offsets, bsum, bucket, out, n_nodes);
}

// Round 14
// 70.336 us; speedup vs baseline: 2.6452x; 1.1710x over previous
//
#include <hip/hip_runtime.h>

#define D        128
#define NT       256
#define CAP      64       // per-dst bucket capacity (avg degree 12.8, max ~35)
#define CSH      4        // counts stride shift (64-B line per counter)
#define OVF_CAP  65536    // overflow list capacity (unused for this input)

typedef __attribute__((ext_vector_type(4))) _Float16 half4;
typedef __attribute__((ext_vector_type(4))) float    f32x4;

__device__ __forceinline__ float4 elu_mul(float4 g, float4 w) {
    float4 v;
    v.x = g.x * w.x; v.y = g.y * w.y; v.z = g.z * w.z; v.w = g.w * w.w;
    v.x = (v.x > 0.0f) ? v.x : (__expf(v.x) - 1.0f);
    v.y = (v.y > 0.0f) ? v.y : (__expf(v.y) - 1.0f);
    v.z = (v.z > 0.0f) ? v.z : (__expf(v.z) - 1.0f);
    v.w = (v.w > 0.0f) ? v.w : (__expf(v.w) - 1.0f);
    return v;
}

// ---------------------------------------------------------------------------
// Fused pre-pass (round-8 structure, best measured):
//   phase 1: issue all edge atomics (<=2/thread), nothing consumes pos yet
//   phase 2: emb = elu(ge*w) fp16 (independent work hides atomic latency)
//   phase 3: consume slots, scatter bucket stores
// ---------------------------------------------------------------------------
__global__ __launch_bounds__(NT)
void fused_pre_kernel(const float* __restrict__ ge, const float* __restrict__ weight,
                      const int* __restrict__ e_feat, const int* __restrict__ src,
                      const int* __restrict__ dst,
                      _Float16* __restrict__ emb, int* __restrict__ counts,
                      unsigned int* __restrict__ bucket,
                      int* __restrict__ ovf_cnt, int* __restrict__ ovf,
                      int n_nodes, int n_edges) {
    const int t = blockIdx.x * NT + threadIdx.x;
    const int T = gridDim.x * NT;

    int e0 = t, e1 = t + T;
    bool v0 = (e0 < n_edges), v1 = (e1 < n_edges);
    int d0 = 0, d1 = 0, pos0 = 0, pos1 = 0;
    unsigned int rec0 = 0, rec1 = 0;
    if (v0) {
        d0 = dst[e0];
        int f0 = e_feat[e0];
        unsigned int flag0 = (f0 == 0 || f0 == 6 || f0 == 14 || f0 == 30) ? 1u : 0u;
        rec0 = (unsigned int)src[e0] | (flag0 << 31);
        pos0 = atomicAdd(&counts[d0 << CSH], 1);
    }
    if (v1) {
        d1 = dst[e1];
        int f1 = e_feat[e1];
        unsigned int flag1 = (f1 == 0 || f1 == 6 || f1 == 14 || f1 == 30) ? 1u : 0u;
        rec1 = (unsigned int)src[e1] | (flag1 << 31);
        pos1 = atomicAdd(&counts[d1 << CSH], 1);
    }

    int quads = n_nodes * (D / 4);
    for (int q = t; q < quads; q += T) {
        int col = (q & 31) * 4;  // 32 quads per row
        float4 g = *reinterpret_cast<const float4*>(ge + (size_t)q * 4);
        float4 w = *reinterpret_cast<const float4*>(weight + col);
        float4 v = elu_mul(g, w);
        half4 h;
        h.x = (_Float16)v.x; h.y = (_Float16)v.y;
        h.z = (_Float16)v.z; h.w = (_Float16)v.w;
        *reinterpret_cast<half4*>(emb + (size_t)q * 4) = h;
    }

    if (v0) {
        if (pos0 < CAP) {
            bucket[((size_t)d0 << 6) + pos0] = rec0;
        } else {
            int op = atomicAdd(ovf_cnt, 1);
            if (op < OVF_CAP) { ovf[2 * op] = d0; ovf[2 * op + 1] = (int)rec0; }
        }
    }
    if (v1) {
        if (pos1 < CAP) {
            bucket[((size_t)d1 << 6) + pos1] = rec1;
        } else {
            int op = atomicAdd(ovf_cnt, 1);
            if (op < OVF_CAP) { ovf[2 * op] = d1; ovf[2 * op + 1] = (int)rec1; }
        }
    }
}

// ---------------------------------------------------------------------------
// Gather: 32 lanes/node, 4 fp16 cols/lane; 8/4/1 unrolled record loop to keep
// 8 random emb loads in flight; nontemporal output store.
// ---------------------------------------------------------------------------
__global__ __launch_bounds__(NT)
void gather_kernel(const _Float16* __restrict__ emb,
                   const int* __restrict__ counts,
                   const unsigned int* __restrict__ bucket,
                   const int* __restrict__ ovf_cnt, const int* __restrict__ ovf,
                   float* __restrict__ out, int n_nodes) {
    int tid = blockIdx.x * NT + threadIdx.x;
    int node = tid >> 5;
    if (node >= n_nodes) return;
    int col = (tid & 31) * 4;

    int cnt = counts[node << CSH];
    if (cnt > CAP) cnt = CAP;
    const unsigned int* bkt = bucket + ((size_t)node << 6);
    float4 acc = make_float4(0.f, 0.f, 0.f, 0.f);

    int i = 0;
    for (; i + 8 <= cnt; i += 8) {
        uint4 ra = *reinterpret_cast<const uint4*>(bkt + i);
        uint4 rb = *reinterpret_cast<const uint4*>(bkt + i + 4);
        half4 h0 = *reinterpret_cast<const half4*>(emb + (size_t)(ra.x & 0x7FFFFFFFu) * D + col);
        half4 h1 = *reinterpret_cast<const half4*>(emb + (size_t)(ra.y & 0x7FFFFFFFu) * D + col);
        half4 h2 = *reinterpret_cast<const half4*>(emb + (size_t)(ra.z & 0x7FFFFFFFu) * D + col);
        half4 h3 = *reinterpret_cast<const half4*>(emb + (size_t)(ra.w & 0x7FFFFFFFu) * D + col);
        half4 h4 = *reinterpret_cast<const half4*>(emb + (size_t)(rb.x & 0x7FFFFFFFu) * D + col);
        half4 h5 = *reinterpret_cast<const half4*>(emb + (size_t)(rb.y & 0x7FFFFFFFu) * D + col);
        half4 h6 = *reinterpret_cast<const half4*>(emb + (size_t)(rb.z & 0x7FFFFFFFu) * D + col);
        half4 h7 = *reinterpret_cast<const half4*>(emb + (size_t)(rb.w & 0x7FFFFFFFu) * D + col);
        float m0 = (ra.x >> 31) ? 2.f : 1.f, m1 = (ra.y >> 31) ? 2.f : 1.f;
        float m2 = (ra.z >> 31) ? 2.f : 1.f, m3 = (ra.w >> 31) ? 2.f : 1.f;
        float m4 = (rb.x >> 31) ? 2.f : 1.f, m5 = (rb.y >> 31) ? 2.f : 1.f;
        float m6 = (rb.z >> 31) ? 2.f : 1.f, m7 = (rb.w >> 31) ? 2.f : 1.f;
        acc.x += (float)h0.x*m0 + (float)h1.x*m1 + (float)h2.x*m2 + (float)h3.x*m3
               + (float)h4.x*m4 + (float)h5.x*m5 + (float)h6.x*m6 + (float)h7.x*m7;
        acc.y += (float)h0.y*m0 + (float)h1.y*m1 + (float)h2.y*m2 + (float)h3.y*m3
               + (float)h4.y*m4 + (float)h5.y*m5 + (float)h6.y*m6 + (float)h7.y*m7;
        acc.z += (float)h0.z*m0 + (float)h1.z*m1 + (float)h2.z*m2 + (float)h3.z*m3
               + (float)h4.z*m4 + (float)h5.z*m5 + (float)h6.z*m6 + (float)h7.z*m7;
        acc.w += (float)h0.w*m0 + (float)h1.w*m1 + (float)h2.w*m2 + (float)h3.w*m3
               + (float)h4.w*m4 + (float)h5.w*m5 + (float)h6.w*m6 + (float)h7.w*m7;
    }
    for (; i + 4 <= cnt; i += 4) {
        uint4 r = *reinterpret_cast<const uint4*>(bkt + i);
        half4 h0 = *reinterpret_cast<const half4*>(emb + (size_t)(r.x & 0x7FFFFFFFu) * D + col);
        half4 h1 = *reinterpret_cast<const half4*>(emb + (size_t)(r.y & 0x7FFFFFFFu) * D + col);
        half4 h2 = *reinterpret_cast<const half4*>(emb + (size_t)(r.z & 0x7FFFFFFFu) * D + col);
        half4 h3 = *reinterpret_cast<const half4*>(emb + (size_t)(r.w & 0x7FFFFFFFu) * D + col);
        float m0 = (r.x >> 31) ? 2.f : 1.f, m1 = (r.y >> 31) ? 2.f : 1.f;
        float m2 = (r.z >> 31) ? 2.f : 1.f, m3 = (r.w >> 31) ? 2.f : 1.f;
        acc.x += (float)h0.x*m0 + (float)h1.x*m1 + (float)h2.x*m2 + (float)h3.x*m3;
        acc.y += (float)h0.y*m0 + (float)h1.y*m1 + (float)h2.y*m2 + (float)h3.y*m3;
        acc.z += (float)h0.z*m0 + (float)h1.z*m1 + (float)h2.z*m2 + (float)h3.z*m3;
        acc.w += (float)h0.w*m0 + (float)h1.w*m1 + (float)h2.w*m2 + (float)h3.w*m3;
    }
    for (; i < cnt; ++i) {
        unsigned int r = bkt[i];
        half4 h = *reinterpret_cast<const half4*>(emb + (size_t)(r & 0x7FFFFFFFu) * D + col);
        float m = (r >> 31) ? 2.f : 1.f;
        acc.x += (float)h.x*m; acc.y += (float)h.y*m;
        acc.z += (float)h.z*m; acc.w += (float)h.w*m;
    }

    // Overflow guard (expected empty)
    int no = *ovf_cnt;
    if (no > 0) {
        if (no > OVF_CAP) no = OVF_CAP;
        for (int k = 0; k < no; ++k) {
            if (ovf[2 * k] == node) {
                unsigned int r = (unsigned int)ovf[2 * k + 1];
                half4 h = *reinterpret_cast<const half4*>(emb + (size_t)(r & 0x7FFFFFFFu) * D + col);
                float m = (r >> 31) ? 2.f : 1.f;
                acc.x += (float)h.x*m; acc.y += (float)h.y*m;
                acc.z += (float)h.z*m; acc.w += (float)h.w*m;
            }
        }
    }

    f32x4 o;
    o.x = acc.x; o.y = acc.y; o.z = acc.z; o.w = acc.w;
    __builtin_nontemporal_store(o, reinterpret_cast<f32x4*>(out + (size_t)node * D + col));
}

// ---------------------------------------------------------------------------
// Fallback (tiny workspace): atomic scatter.
// ---------------------------------------------------------------------------
__global__ void edge_scatter_fallback(const float* __restrict__ ge,
                                      const float* __restrict__ weight,
                                      const int* __restrict__ e_feat,
                                      const int* __restrict__ src,
                                      const int* __restrict__ dst,
                                      float* __restrict__ out, int n_edges) {
    long long tid = (long long)blockIdx.x * blockDim.x + threadIdx.x;
    int edge = (int)(tid >> 5);
    if (edge >= n_edges) return;
    int col = (int)(tid & 31) * 4;
    int e = e_feat[edge];
    float mult = (e == 0 || e == 6 || e == 14 || e == 30) ? 2.0f : 1.0f;
    float4 w = *reinterpret_cast<const float4*>(weight + col);
    float4 g = *reinterpret_cast<const float4*>(ge + (long long)src[edge] * D + col);
    float4 v = elu_mul(g, w);
    float* o = out + (long long)dst[edge] * D + col;
    atomicAdd(o + 0, v.x * mult);
    atomicAdd(o + 1, v.y * mult);
    atomicAdd(o + 2, v.z * mult);
    atomicAdd(o + 3, v.w * mult);
}

extern "C" void kernel_launch(void* const* d_in, const int* in_sizes, int n_in,
                              void* d_out, int out_size, void* d_ws, size_t ws_size,
                              hipStream_t stream) {
    const float* ge     = (const float*)d_in[0];   // [N, 128]
    const float* weight = (const float*)d_in[1];   // [1, 128]
    const int*   e_feat = (const int*)d_in[2];     // [E]
    const int*   src    = (const int*)d_in[3];     // [E]
    const int*   dst    = (const int*)d_in[4];     // [E]
    float* out = (float*)d_out;                    // [N, 128]

    int n_edges = in_sizes[2];
    int n_nodes = out_size / D;

    // Workspace: emb | counts (padded, 64 B/node) | ovf_cnt | bucket | ovf
    auto align256 = [](size_t x) { return (x + 255) & ~(size_t)255; };
    size_t o_emb    = 0;
    size_t o_counts = o_emb    + align256((size_t)n_nodes * D * sizeof(_Float16));
    size_t o_ovfcnt = o_counts + align256((size_t)n_nodes * 64);
    size_t o_bucket = o_ovfcnt + 256;
    size_t o_ovf    = o_bucket + align256((size_t)n_nodes * CAP * 4);
    size_t need     = o_ovf + (size_t)OVF_CAP * 8 + 256;

    const int GRID = 2048;
    bool fits = ((long long)n_edges <= 2LL * GRID * NT);

    if (ws_size < need || !fits) {
        (void)hipMemsetAsync(d_out, 0, (size_t)out_size * sizeof(float), stream);
        long long total = (long long)n_edges * 32;
        edge_scatter_fallback<<<(int)((total + 255) / 256), 256, 0, stream>>>(
            ge, weight, e_feat, src, dst, out, n_edges);
        return;
    }

    char* ws = (char*)d_ws;
    _Float16*     emb     = (_Float16*)(ws + o_emb);
    int*          counts  = (int*)(ws + o_counts);
    int*          ovf_cnt = (int*)(ws + o_ovfcnt);
    unsigned int* bucket  = (unsigned int*)(ws + o_bucket);
    int*          ovf     = (int*)(ws + o_ovf);

    // One memset covers padded counts + ovf_cnt (contiguous).
    (void)hipMemsetAsync(counts, 0, (o_bucket - o_counts), stream);

    fused_pre_kernel<<<GRID, NT, 0, stream>>>(ge, weight, e_feat, src, dst,
                                              emb, counts, bucket, ovf_cnt, ovf,
                                              n_nodes, n_edges);

    long long total = (long long)n_nodes * 32;
    gather_kernel<<<(int)((total + 255) / 256), NT, 0, stream>>>(
        emb, counts, bucket, ovf_cnt, ovf, out, n_nodes);
}

// Round 15
// 63.538 us; speedup vs baseline: 2.9282x; 1.1070x over previous
//
#include <hip/hip_runtime.h>

#define D        128
#define NT       256
#define NBMAX    256       // max coarse bins supported (n_nodes <= 65536)
#define CAPB     8192      // binned records per bin (mean ~3277 for this input)
#define KA_BLKS  320
#define OVF_CAP  65536

typedef __attribute__((ext_vector_type(4))) _Float16 half4;
typedef __attribute__((ext_vector_type(4))) float    f32x4;

__device__ __forceinline__ float4 elu_mul(float4 g, float4 w) {
    float4 v;
    v.x = g.x * w.x; v.y = g.y * w.y; v.z = g.z * w.z; v.w = g.w * w.w;
    v.x = (v.x > 0.0f) ? v.x : (__expf(v.x) - 1.0f);
    v.y = (v.y > 0.0f) ? v.y : (__expf(v.y) - 1.0f);
    v.z = (v.z > 0.0f) ? v.z : (__expf(v.z) - 1.0f);
    v.w = (v.w > 0.0f) ? v.w : (__expf(v.w) - 1.0f);
    return v;
}

// ---------------------------------------------------------------------------
// K1: emb = elu(ge*w) fp16 + init bin cursors (cursor[b] = b*CAPB) + ovf_cnt.
// ---------------------------------------------------------------------------
__global__ __launch_bounds__(NT)
void emb_kernel(const float* __restrict__ ge, const float* __restrict__ weight,
                _Float16* __restrict__ emb, int* __restrict__ cursor,
                int* __restrict__ ovf_cnt, int n_nodes, int nbins) {
    int t = blockIdx.x * NT + threadIdx.x;
    if (t < nbins) cursor[t] = t * CAPB;
    if (t == 0) *ovf_cnt = 0;

    int quads = n_nodes * (D / 4);
    if (t < quads) {
        int col = (t & 31) * 4;
        float4 g = *reinterpret_cast<const float4*>(ge + (size_t)t * 4);
        float4 w = *reinterpret_cast<const float4*>(weight + col);
        float4 v = elu_mul(g, w);
        half4 h;
        h.x = (_Float16)v.x; h.y = (_Float16)v.y;
        h.z = (_Float16)v.z; h.w = (_Float16)v.w;
        *reinterpret_cast<half4*>(emb + (size_t)t * 4) = h;
    }
}

// ---------------------------------------------------------------------------
// K2: coarse binning by dst>>8. Per-block LDS histogram -> one global atomic
//     per (block,bin) -> LDS-ranked scatter of uint2{rec, dst&255}. Each
//     block's claim per bin is contiguous (line-dense stores).
// ---------------------------------------------------------------------------
__global__ __launch_bounds__(NT)
void bin_kernel(const int* __restrict__ e_feat, const int* __restrict__ src,
                const int* __restrict__ dst, int* __restrict__ cursor,
                uint2* __restrict__ binned, int* __restrict__ ovf_cnt,
                uint2* __restrict__ ovf, int n_edges, int nbins, int per_block) {
    __shared__ int hist[NBMAX];
    __shared__ int base[NBMAX];
    __shared__ int rk[NBMAX];
    int t = threadIdx.x;
    for (int i = t; i < NBMAX; i += NT) { hist[i] = 0; rk[i] = 0; }
    __syncthreads();

    int e0 = blockIdx.x * per_block;
    int e1 = e0 + per_block; if (e1 > n_edges) e1 = n_edges;

    for (int e = e0 + t; e < e1; e += NT)
        atomicAdd(&hist[dst[e] >> 8], 1);
    __syncthreads();

    for (int b = t; b < nbins; b += NT)
        base[b] = hist[b] ? atomicAdd(&cursor[b], hist[b]) : 0;
    __syncthreads();

    for (int e = e0 + t; e < e1; e += NT) {
        int d = dst[e];
        int b = d >> 8;
        int f = e_feat[e];
        unsigned int flag = (f == 0 || f == 6 || f == 14 || f == 30) ? 1u : 0u;
        unsigned int rec  = (unsigned int)src[e] | (flag << 31);
        int r = atomicAdd(&rk[b], 1);
        long long pos = (long long)base[b] + r;
        if (pos < (long long)(b + 1) * CAPB) {
            binned[pos] = make_uint2(rec, (unsigned int)(d & 255));
        } else {
            int op = atomicAdd(ovf_cnt, 1);
            if (op < OVF_CAP) ovf[op] = make_uint2(rec, (unsigned int)d);
        }
    }
}

// ---------------------------------------------------------------------------
// K3: per-bin CSR build + fill. One 1024-thread block per bin. Bin bases via
//     redundant LDS scan of bin counts; node offsets via LDS histogram+scan;
//     records scattered into the bin's contiguous bucket region (one block =
//     one XCD owns each bucket line -> full-line writebacks).
// ---------------------------------------------------------------------------
__global__ __launch_bounds__(1024)
void csr_kernel(const uint2* __restrict__ binned, const int* __restrict__ cursor,
                int* __restrict__ offsets, unsigned int* __restrict__ bucket,
                int n_nodes, int nbins) {
    __shared__ int s[NBMAX];
    __shared__ int cnt2[NBMAX];
    __shared__ int off2[NBMAX];
    __shared__ int rk2[NBMAX];
    int t = threadIdx.x;
    int b = blockIdx.x;

    // --- bin counts + scan for global bin bases --------------------------
    int c = 0;
    if (t < nbins) {
        int raw = cursor[t] - t * CAPB;
        c = raw < CAPB ? raw : CAPB;
    }
    if (t < NBMAX) s[t] = c;
    __syncthreads();
    for (int d = 1; d < NBMAX; d <<= 1) {
        int x = 0;
        if (t < NBMAX && t >= d) x = s[t - d];
        __syncthreads();
        if (t < NBMAX) s[t] += x;
        __syncthreads();
    }
    int rawb = cursor[b] - b * CAPB;
    int cntb = rawb < CAPB ? rawb : CAPB;
    int G = s[b] - cntb;               // exclusive prefix (s inclusive)
    int total = s[nbins - 1];

    // --- node-local histogram over dst&255 -------------------------------
    for (int i = t; i < NBMAX; i += 1024) { cnt2[i] = 0; rk2[i] = 0; }
    __syncthreads();
    const uint2* rb = binned + (long long)b * CAPB;
    for (int i = t; i < cntb; i += 1024)
        atomicAdd(&cnt2[rb[i].y], 1);
    __syncthreads();
    if (t < NBMAX) off2[t] = cnt2[t];
    __syncthreads();
    for (int d = 1; d < NBMAX; d <<= 1) {
        int x = 0;
        if (t < NBMAX && t >= d) x = off2[t - d];
        __syncthreads();
        if (t < NBMAX) off2[t] += x;
        __syncthreads();
    }
    // off2 inclusive; exclusive = off2[l] - cnt2[l]

    // --- write CSR offsets ------------------------------------------------
    int base_node = b << 8;
    if (t < NBMAX) {
        int node = base_node + t;
        if (node <= n_nodes) offsets[node] = G + off2[t] - cnt2[t];
    }
    if (b == nbins - 1 && t == 0) offsets[n_nodes] = total;
    __syncthreads();

    // --- scatter records into contiguous bucket region --------------------
    for (int i = t; i < cntb; i += 1024) {
        uint2 r = rb[i];
        int l = (int)r.y;
        int p = atomicAdd(&rk2[l], 1);
        bucket[G + (off2[l] - cnt2[l]) + p] = r.x;
    }
}

// ---------------------------------------------------------------------------
// K4: gather. 32 lanes/node, 4 fp16 cols/lane; 8/4/1 unrolled; nt store.
// ---------------------------------------------------------------------------
__global__ __launch_bounds__(NT)
void gather_kernel(const _Float16* __restrict__ emb,
                   const int* __restrict__ offsets,
                   const unsigned int* __restrict__ bucket,
                   const int* __restrict__ ovf_cnt, const uint2* __restrict__ ovf,
                   float* __restrict__ out, int n_nodes) {
    int tid = blockIdx.x * NT + threadIdx.x;
    int node = tid >> 5;
    if (node >= n_nodes) return;
    int col = (tid & 31) * 4;

    int beg = offsets[node];
    int end = offsets[node + 1];
    float4 acc = make_float4(0.f, 0.f, 0.f, 0.f);

    int i = beg;
    for (; i + 8 <= end; i += 8) {
        unsigned int r0 = bucket[i+0], r1 = bucket[i+1], r2 = bucket[i+2], r3 = bucket[i+3];
        unsigned int r4 = bucket[i+4], r5 = bucket[i+5], r6 = bucket[i+6], r7 = bucket[i+7];
        half4 h0 = *reinterpret_cast<const half4*>(emb + (size_t)(r0 & 0x7FFFFFFFu) * D + col);
        half4 h1 = *reinterpret_cast<const half4*>(emb + (size_t)(r1 & 0x7FFFFFFFu) * D + col);
        half4 h2 = *reinterpret_cast<const half4*>(emb + (size_t)(r2 & 0x7FFFFFFFu) * D + col);
        half4 h3 = *reinterpret_cast<const half4*>(emb + (size_t)(r3 & 0x7FFFFFFFu) * D + col);
        half4 h4 = *reinterpret_cast<const half4*>(emb + (size_t)(r4 & 0x7FFFFFFFu) * D + col);
        half4 h5 = *reinterpret_cast<const half4*>(emb + (size_t)(r5 & 0x7FFFFFFFu) * D + col);
        half4 h6 = *reinterpret_cast<const half4*>(emb + (size_t)(r6 & 0x7FFFFFFFu) * D + col);
        half4 h7 = *reinterpret_cast<const half4*>(emb + (size_t)(r7 & 0x7FFFFFFFu) * D + col);
        float m0 = (r0 >> 31) ? 2.f : 1.f, m1 = (r1 >> 31) ? 2.f : 1.f;
        float m2 = (r2 >> 31) ? 2.f : 1.f, m3 = (r3 >> 31) ? 2.f : 1.f;
        float m4 = (r4 >> 31) ? 2.f : 1.f, m5 = (r5 >> 31) ? 2.f : 1.f;
        float m6 = (r6 >> 31) ? 2.f : 1.f, m7 = (r7 >> 31) ? 2.f : 1.f;
        acc.x += (float)h0.x*m0 + (float)h1.x*m1 + (float)h2.x*m2 + (float)h3.x*m3
               + (float)h4.x*m4 + (float)h5.x*m5 + (float)h6.x*m6 + (float)h7.x*m7;
        acc.y += (float)h0.y*m0 + (float)h1.y*m1 + (float)h2.y*m2 + (float)h3.y*m3
               + (float)h4.y*m4 + (float)h5.y*m5 + (float)h6.y*m6 + (float)h7.y*m7;
        acc.z += (float)h0.z*m0 + (float)h1.z*m1 + (float)h2.z*m2 + (float)h3.z*m3
               + (float)h4.z*m4 + (float)h5.z*m5 + (float)h6.z*m6 + (float)h7.z*m7;
        acc.w += (float)h0.w*m0 + (float)h1.w*m1 + (float)h2.w*m2 + (float)h3.w*m3
               + (float)h4.w*m4 + (float)h5.w*m5 + (float)h6.w*m6 + (float)h7.w*m7;
    }
    for (; i + 4 <= end; i += 4) {
        unsigned int r0 = bucket[i+0], r1 = bucket[i+1], r2 = bucket[i+2], r3 = bucket[i+3];
        half4 h0 = *reinterpret_cast<const half4*>(emb + (size_t)(r0 & 0x7FFFFFFFu) * D + col);
        half4 h1 = *reinterpret_cast<const half4*>(emb + (size_t)(r1 & 0x7FFFFFFFu) * D + col);
        half4 h2 = *reinterpret_cast<const half4*>(emb + (size_t)(r2 & 0x7FFFFFFFu) * D + col);
        half4 h3 = *reinterpret_cast<const half4*>(emb + (size_t)(r3 & 0x7FFFFFFFu) * D + col);
        float m0 = (r0 >> 31) ? 2.f : 1.f, m1 = (r1 >> 31) ? 2.f : 1.f;
        float m2 = (r2 >> 31) ? 2.f : 1.f, m3 = (r3 >> 31) ? 2.f : 1.f;
        acc.x += (float)h0.x*m0 + (float)h1.x*m1 + (float)h2.x*m2 + (float)h3.x*m3;
        acc.y += (float)h0.y*m0 + (float)h1.y*m1 + (float)h2.y*m2 + (float)h3.y*m3;
        acc.z += (float)h0.z*m0 + (float)h1.z*m1 + (float)h2.z*m2 + (float)h3.z*m3;
        acc.w += (float)h0.w*m0 + (float)h1.w*m1 + (float)h2.w*m2 + (float)h3.w*m3;
    }
    for (; i < end; ++i) {
        unsigned int r = bucket[i];
        half4 h = *reinterpret_cast<const half4*>(emb + (size_t)(r & 0x7FFFFFFFu) * D + col);
        float m = (r >> 31) ? 2.f : 1.f;
        acc.x += (float)h.x*m; acc.y += (float)h.y*m;
        acc.z += (float)h.z*m; acc.w += (float)h.w*m;
    }

    // Overflow guard (expected empty)
    int no = *ovf_cnt;
    if (no > 0) {
        if (no > OVF_CAP) no = OVF_CAP;
        for (int k = 0; k < no; ++k) {
            uint2 o = ovf[k];
            if ((int)o.y == node) {
                half4 h = *reinterpret_cast<const half4*>(emb + (size_t)(o.x & 0x7FFFFFFFu) * D + col);
                float m = (o.x >> 31) ? 2.f : 1.f;
                acc.x += (float)h.x*m; acc.y += (float)h.y*m;
                acc.z += (float)h.z*m; acc.w += (float)h.w*m;
            }
        }
    }

    f32x4 o;
    o.x = acc.x; o.y = acc.y; o.z = acc.z; o.w = acc.w;
    __builtin_nontemporal_store(o, reinterpret_cast<f32x4*>(out + (size_t)node * D + col));
}

// ---------------------------------------------------------------------------
// Fallback: atomic scatter.
// ---------------------------------------------------------------------------
__global__ void edge_scatter_fallback(const float* __restrict__ ge,
                                      const float* __restrict__ weight,
                                      const int* __restrict__ e_feat,
                                      const int* __restrict__ src,
                                      const int* __restrict__ dst,
                                      float* __restrict__ out, int n_edges) {
    long long tid = (long long)blockIdx.x * blockDim.x + threadIdx.x;
    int edge = (int)(tid >> 5);
    if (edge >= n_edges) return;
    int col = (int)(tid & 31) * 4;
    int e = e_feat[edge];
    float mult = (e == 0 || e == 6 || e == 14 || e == 30) ? 2.0f : 1.0f;
    float4 w = *reinterpret_cast<const float4*>(weight + col);
    float4 g = *reinterpret_cast<const float4*>(ge + (long long)src[edge] * D + col);
    float4 v = elu_mul(g, w);
    float* o = out + (long long)dst[edge] * D + col;
    atomicAdd(o + 0, v.x * mult);
    atomicAdd(o + 1, v.y * mult);
    atomicAdd(o + 2, v.z * mult);
    atomicAdd(o + 3, v.w * mult);
}

extern "C" void kernel_launch(void* const* d_in, const int* in_sizes, int n_in,
                              void* d_out, int out_size, void* d_ws, size_t ws_size,
                              hipStream_t stream) {
    const float* ge     = (const float*)d_in[0];   // [N, 128]
    const float* weight = (const float*)d_in[1];   // [1, 128]
    const int*   e_feat = (const int*)d_in[2];     // [E]
    const int*   src    = (const int*)d_in[3];     // [E]
    const int*   dst    = (const int*)d_in[4];     // [E]
    float* out = (float*)d_out;                    // [N, 128]

    int n_edges = in_sizes[2];
    int n_nodes = out_size / D;
    int nbins   = (n_nodes + 255) >> 8;            // 196 for N=50000

    // Workspace: emb | cursor | ovf_cnt | offsets | binned | bucket | ovf
    auto align256 = [](size_t x) { return (x + 255) & ~(size_t)255; };
    size_t o_emb    = 0;
    size_t o_cursor = o_emb    + align256((size_t)n_nodes * D * sizeof(_Float16));
    size_t o_ovfcnt = o_cursor + align256((size_t)NBMAX * 4);
    size_t o_offs   = o_ovfcnt + 256;
    size_t o_binned = o_offs   + align256((size_t)(n_nodes + 1) * 4);
    size_t o_bucket = o_binned + align256((size_t)NBMAX * CAPB * 8);
    size_t o_ovf    = o_bucket + align256((size_t)n_edges * 4);
    size_t need     = o_ovf + (size_t)OVF_CAP * 8 + 256;

    // Need: bins fit, per-bin avg degree consistent with CAPB safety margin.
    bool ok = (nbins <= NBMAX) && ((long long)n_edges <= (long long)nbins * CAPB);

    if (ws_size < need || !ok) {
        (void)hipMemsetAsync(d_out, 0, (size_t)out_size * sizeof(float), stream);
        long long total = (long long)n_edges * 32;
        edge_scatter_fallback<<<(int)((total + 255) / 256), 256, 0, stream>>>(
            ge, weight, e_feat, src, dst, out, n_edges);
        return;
    }

    char* ws = (char*)d_ws;
    _Float16*     emb     = (_Float16*)(ws + o_emb);
    int*          cursor  = (int*)(ws + o_cursor);
    int*          ovf_cnt = (int*)(ws + o_ovfcnt);
    int*          offsets = (int*)(ws + o_offs);
    uint2*        binned  = (uint2*)(ws + o_binned);
    unsigned int* bucket  = (unsigned int*)(ws + o_bucket);
    uint2*        ovf     = (uint2*)(ws + o_ovf);

    int quads = n_nodes * (D / 4);
    int k1b = (quads + NT - 1) / NT;
    int per_block = (n_edges + KA_BLKS - 1) / KA_BLKS;

    emb_kernel<<<k1b, NT, 0, stream>>>(ge, weight, emb, cursor, ovf_cnt,
                                       n_nodes, nbins);
    bin_kernel<<<KA_BLKS, NT, 0, stream>>>(e_feat, src, dst, cursor, binned,
                                           ovf_cnt, ovf, n_edges, nbins, per_block);
    csr_kernel<<<nbins, 1024, 0, stream>>>(binned, cursor, offsets, bucket,
                                           n_nodes, nbins);

    long long total = (long long)n_nodes * 32;
    gather_kernel<<<(int)((total + 255) / 256), NT, 0, stream>>>(
        emb, offsets, bucket, ovf_cnt, ovf, out, n_nodes);
}

// Round 16
// 57.162 us; speedup vs baseline: 3.2549x; 1.1116x over previous
//
#include <hip/hip_runtime.h>

#define D      128
#define NT     256
#define KB     320       // bin blocks (edge partition)
#define CAPBB  64        // records per (block,bin) cell
#define NBMAX  256       // max bins => n_nodes <= 65536

typedef __attribute__((ext_vector_type(4))) _Float16 half4;
typedef __attribute__((ext_vector_type(4))) float    f32x4;

__device__ __forceinline__ float4 elu_mul(float4 g, float4 w) {
    float4 v;
    v.x = g.x * w.x; v.y = g.y * w.y; v.z = g.z * w.z; v.w = g.w * w.w;
    v.x = (v.x > 0.0f) ? v.x : (__expf(v.x) - 1.0f);
    v.y = (v.y > 0.0f) ? v.y : (__expf(v.y) - 1.0f);
    v.z = (v.z > 0.0f) ? v.z : (__expf(v.z) - 1.0f);
    v.w = (v.w > 0.0f) ? v.w : (__expf(v.w) - 1.0f);
    return v;
}

// ---------------------------------------------------------------------------
// K1 (fused): blocks [0,KB): deterministic binning into private (blk,bin)
// cells — LDS rank only, NO global atomics, NO init needed (cnts/spill_cnt
// written unconditionally). Blocks [KB,...): emb = elu(ge*w) fp16.
// ---------------------------------------------------------------------------
__global__ __launch_bounds__(NT)
void fused_kernel(const float* __restrict__ ge, const float* __restrict__ weight,
                  const int* __restrict__ e_feat, const int* __restrict__ src,
                  const int* __restrict__ dst,
                  _Float16* __restrict__ emb, uint2* __restrict__ binned,
                  int* __restrict__ cnts, uint2* __restrict__ spill,
                  int* __restrict__ spill_cnt,
                  int n_nodes, int n_edges, int nbins, int per_block) {
    if ((int)blockIdx.x < KB) {
        __shared__ int rk[NBMAX];
        __shared__ int sp;
        int t = threadIdx.x;
        for (int i = t; i < NBMAX; i += NT) rk[i] = 0;
        if (t == 0) sp = 0;
        __syncthreads();

        int blk = blockIdx.x;
        int e0 = blk * per_block;
        int e1 = e0 + per_block; if (e1 > n_edges) e1 = n_edges;
        for (int e = e0 + t; e < e1; e += NT) {
            int d = dst[e];
            int b = d >> 8;
            int f = e_feat[e];
            unsigned int flag = (f == 0 || f == 6 || f == 14 || f == 30) ? 1u : 0u;
            unsigned int rec  = (unsigned int)src[e] | (flag << 31);
            int r = atomicAdd(&rk[b], 1);
            if (r < CAPBB) {
                binned[((size_t)blk * nbins + b) * CAPBB + r] =
                    make_uint2(rec, (unsigned int)(d & 255));
            } else {
                int s = atomicAdd(&sp, 1);
                spill[(size_t)blk * per_block + s] = make_uint2(rec, (unsigned int)d);
            }
        }
        __syncthreads();
        for (int b = t; b < nbins; b += NT)
            cnts[blk * nbins + b] = rk[b] < CAPBB ? rk[b] : CAPBB;
        if (t == 0) spill_cnt[blk] = sp;
    } else {
        int t = ((int)blockIdx.x - KB) * NT + threadIdx.x;
        int quads = n_nodes * (D / 4);
        if (t < quads) {
            int col = (t & 31) * 4;
            float4 g = *reinterpret_cast<const float4*>(ge + (size_t)t * 4);
            float4 w = *reinterpret_cast<const float4*>(weight + col);
            float4 v = elu_mul(g, w);
            half4 h;
            h.x = (_Float16)v.x; h.y = (_Float16)v.y;
            h.z = (_Float16)v.z; h.w = (_Float16)v.w;
            *reinterpret_cast<half4*>(emb + (size_t)t * 4) = h;
        }
    }
}

// ---------------------------------------------------------------------------
// K2: per-bin CSR pack. One 1024-thread block per bin; threads 0..KB own one
// cell each. Node histogram + LDS scan -> offdeg{off,deg}; pack records into
// the bin's static contiguous bucket region (base = b*capb_out). Block 0
// also publishes the spill total.
// ---------------------------------------------------------------------------
__global__ __launch_bounds__(1024)
void csr_kernel(const uint2* __restrict__ binned, const int* __restrict__ cnts,
                uint2* __restrict__ offdeg, unsigned int* __restrict__ bucket,
                const int* __restrict__ spill_cnt, int* __restrict__ spill_total,
                int n_nodes, int nbins, int capb_out) {
    __shared__ int cnt2[NBMAX];
    __shared__ int off2[NBMAX];
    __shared__ int rk2[NBMAX];
    __shared__ int cellc[KB];
    __shared__ int stot;
    int t = threadIdx.x;
    int b = blockIdx.x;

    for (int i = t; i < NBMAX; i += 1024) { cnt2[i] = 0; rk2[i] = 0; }
    if (t < KB) cellc[t] = cnts[t * nbins + b];
    if (t == 0) stot = 0;
    __syncthreads();

    // phase A: node-local histogram over dst&255
    if (t < KB) {
        const uint2* cell = binned + ((size_t)t * nbins + b) * CAPBB;
        int c = cellc[t];
        for (int j = 0; j < c; ++j) atomicAdd(&cnt2[cell[j].y], 1);
    }
    __syncthreads();

    // inclusive scan over 256 node slots
    if (t < NBMAX) off2[t] = cnt2[t];
    __syncthreads();
    for (int d2 = 1; d2 < NBMAX; d2 <<= 1) {
        int x = 0;
        if (t < NBMAX && t >= d2) x = off2[t - d2];
        __syncthreads();
        if (t < NBMAX) off2[t] += x;
        __syncthreads();
    }

    int G = b * capb_out;
    if (t < NBMAX) {
        int node = (b << 8) + t;
        if (node < n_nodes)
            offdeg[node] = make_uint2((unsigned int)(G + off2[t] - cnt2[t]),
                                      (unsigned int)cnt2[t]);
    }
    __syncthreads();

    // phase C: pack records (grouped by node) into contiguous region
    if (t < KB) {
        const uint2* cell = binned + ((size_t)t * nbins + b) * CAPBB;
        int c = cellc[t];
        for (int j = 0; j < c; ++j) {
            uint2 r = cell[j];
            int l = (int)r.y;
            int p = atomicAdd(&rk2[l], 1);
            bucket[G + (off2[l] - cnt2[l]) + p] = r.x;
        }
    }

    if (b == 0) {
        if (t < KB && spill_cnt[t] > 0) atomicAdd(&stot, spill_cnt[t]);
        __syncthreads();
        if (t == 0) *spill_total = stot;
    }
}

// ---------------------------------------------------------------------------
// K3: gather. 32 lanes/node, 4 fp16 cols/lane; one uint2 offdeg broadcast
// load; 8/4/1 unrolled record loop; nontemporal output store.
// ---------------------------------------------------------------------------
__global__ __launch_bounds__(NT)
void gather_kernel(const _Float16* __restrict__ emb,
                   const uint2* __restrict__ offdeg,
                   const unsigned int* __restrict__ bucket,
                   const int* __restrict__ spill_total,
                   const int* __restrict__ spill_cnt,
                   const uint2* __restrict__ spill,
                   float* __restrict__ out, int n_nodes, int per_block) {
    int tid = blockIdx.x * NT + threadIdx.x;
    int node = tid >> 5;
    if (node >= n_nodes) return;
    int col = (tid & 31) * 4;

    uint2 od = offdeg[node];
    int beg = (int)od.x;
    int end = beg + (int)od.y;
    float4 acc = make_float4(0.f, 0.f, 0.f, 0.f);

    int i = beg;
    for (; i + 8 <= end; i += 8) {
        unsigned int r0 = bucket[i+0], r1 = bucket[i+1], r2 = bucket[i+2], r3 = bucket[i+3];
        unsigned int r4 = bucket[i+4], r5 = bucket[i+5], r6 = bucket[i+6], r7 = bucket[i+7];
        half4 h0 = *reinterpret_cast<const half4*>(emb + (size_t)(r0 & 0x7FFFFFFFu) * D + col);
        half4 h1 = *reinterpret_cast<const half4*>(emb + (size_t)(r1 & 0x7FFFFFFFu) * D + col);
        half4 h2 = *reinterpret_cast<const half4*>(emb + (size_t)(r2 & 0x7FFFFFFFu) * D + col);
        half4 h3 = *reinterpret_cast<const half4*>(emb + (size_t)(r3 & 0x7FFFFFFFu) * D + col);
        half4 h4 = *reinterpret_cast<const half4*>(emb + (size_t)(r4 & 0x7FFFFFFFu) * D + col);
        half4 h5 = *reinterpret_cast<const half4*>(emb + (size_t)(r5 & 0x7FFFFFFFu) * D + col);
        half4 h6 = *reinterpret_cast<const half4*>(emb + (size_t)(r6 & 0x7FFFFFFFu) * D + col);
        half4 h7 = *reinterpret_cast<const half4*>(emb + (size_t)(r7 & 0x7FFFFFFFu) * D + col);
        float m0 = (r0 >> 31) ? 2.f : 1.f, m1 = (r1 >> 31) ? 2.f : 1.f;
        float m2 = (r2 >> 31) ? 2.f : 1.f, m3 = (r3 >> 31) ? 2.f : 1.f;
        float m4 = (r4 >> 31) ? 2.f : 1.f, m5 = (r5 >> 31) ? 2.f : 1.f;
        float m6 = (r6 >> 31) ? 2.f : 1.f, m7 = (r7 >> 31) ? 2.f : 1.f;
        acc.x += (float)h0.x*m0 + (float)h1.x*m1 + (float)h2.x*m2 + (float)h3.x*m3
               + (float)h4.x*m4 + (float)h5.x*m5 + (float)h6.x*m6 + (float)h7.x*m7;
        acc.y += (float)h0.y*m0 + (float)h1.y*m1 + (float)h2.y*m2 + (float)h3.y*m3
               + (float)h4.y*m4 + (float)h5.y*m5 + (float)h6.y*m6 + (float)h7.y*m7;
        acc.z += (float)h0.z*m0 + (float)h1.z*m1 + (float)h2.z*m2 + (float)h3.z*m3
               + (float)h4.z*m4 + (float)h5.z*m5 + (float)h6.z*m6 + (float)h7.z*m7;
        acc.w += (float)h0.w*m0 + (float)h1.w*m1 + (float)h2.w*m2 + (float)h3.w*m3
               + (float)h4.w*m4 + (float)h5.w*m5 + (float)h6.w*m6 + (float)h7.w*m7;
    }
    for (; i + 4 <= end; i += 4) {
        unsigned int r0 = bucket[i+0], r1 = bucket[i+1], r2 = bucket[i+2], r3 = bucket[i+3];
        half4 h0 = *reinterpret_cast<const half4*>(emb + (size_t)(r0 & 0x7FFFFFFFu) * D + col);
        half4 h1 = *reinterpret_cast<const half4*>(emb + (size_t)(r1 & 0x7FFFFFFFu) * D + col);
        half4 h2 = *reinterpret_cast<const half4*>(emb + (size_t)(r2 & 0x7FFFFFFFu) * D + col);
        half4 h3 = *reinterpret_cast<const half4*>(emb + (size_t)(r3 & 0x7FFFFFFFu) * D + col);
        float m0 = (r0 >> 31) ? 2.f : 1.f, m1 = (r1 >> 31) ? 2.f : 1.f;
        float m2 = (r2 >> 31) ? 2.f : 1.f, m3 = (r3 >> 31) ? 2.f : 1.f;
        acc.x += (float)h0.x*m0 + (float)h1.x*m1 + (float)h2.x*m2 + (float)h3.x*m3;
        acc.y += (float)h0.y*m0 + (float)h1.y*m1 + (float)h2.y*m2 + (float)h3.y*m3;
        acc.z += (float)h0.z*m0 + (float)h1.z*m1 + (float)h2.z*m2 + (float)h3.z*m3;
        acc.w += (float)h0.w*m0 + (float)h1.w*m1 + (float)h2.w*m2 + (float)h3.w*m3;
    }
    for (; i < end; ++i) {
        unsigned int r = bucket[i];
        half4 h = *reinterpret_cast<const half4*>(emb + (size_t)(r & 0x7FFFFFFFu) * D + col);
        float m = (r >> 31) ? 2.f : 1.f;
        acc.x += (float)h.x*m; acc.y += (float)h.y*m;
        acc.z += (float)h.z*m; acc.w += (float)h.w*m;
    }

    // Spill guard (expected zero; slow-but-correct path for adversarial input)
    if (*spill_total > 0) {
        for (int blk = 0; blk < KB; ++blk) {
            int sc = spill_cnt[blk];
            for (int j = 0; j < sc; ++j) {
                uint2 o = spill[(size_t)blk * per_block + j];
                if ((int)o.y == node) {
                    half4 h = *reinterpret_cast<const half4*>(emb + (size_t)(o.x & 0x7FFFFFFFu) * D + col);
                    float m = (o.x >> 31) ? 2.f : 1.f;
                    acc.x += (float)h.x*m; acc.y += (float)h.y*m;
                    acc.z += (float)h.z*m; acc.w += (float)h.w*m;
                }
            }
        }
    }

    f32x4 o;
    o.x = acc.x; o.y = acc.y; o.z = acc.z; o.w = acc.w;
    __builtin_nontemporal_store(o, reinterpret_cast<f32x4*>(out + (size_t)node * D + col));
}

// ---------------------------------------------------------------------------
// Fallback: atomic scatter.
// ---------------------------------------------------------------------------
__global__ void edge_scatter_fallback(const float* __restrict__ ge,
                                      const float* __restrict__ weight,
                                      const int* __restrict__ e_feat,
                                      const int* __restrict__ src,
                                      const int* __restrict__ dst,
                                      float* __restrict__ out, int n_edges) {
    long long tid = (long long)blockIdx.x * blockDim.x + threadIdx.x;
    int edge = (int)(tid >> 5);
    if (edge >= n_edges) return;
    int col = (int)(tid & 31) * 4;
    int e = e_feat[edge];
    float mult = (e == 0 || e == 6 || e == 14 || e == 30) ? 2.0f : 1.0f;
    float4 w = *reinterpret_cast<const float4*>(weight + col);
    float4 g = *reinterpret_cast<const float4*>(ge + (long long)src[edge] * D + col);
    float4 v = elu_mul(g, w);
    float* o = out + (long long)dst[edge] * D + col;
    atomicAdd(o + 0, v.x * mult);
    atomicAdd(o + 1, v.y * mult);
    atomicAdd(o + 2, v.z * mult);
    atomicAdd(o + 3, v.w * mult);
}

extern "C" void kernel_launch(void* const* d_in, const int* in_sizes, int n_in,
                              void* d_out, int out_size, void* d_ws, size_t ws_size,
                              hipStream_t stream) {
    const float* ge     = (const float*)d_in[0];   // [N, 128]
    const float* weight = (const float*)d_in[1];   // [1, 128]
    const int*   e_feat = (const int*)d_in[2];     // [E]
    const int*   src    = (const int*)d_in[3];     // [E]
    const int*   dst    = (const int*)d_in[4];     // [E]
    float* out = (float*)d_out;                    // [N, 128]

    int n_edges = in_sizes[2];
    int n_nodes = out_size / D;
    int nbins   = (n_nodes + 255) >> 8;            // 196 for N=50000
    int per_block = (n_edges + KB - 1) / KB;       // 2000 for E=640000
    int capb_out  = KB * CAPBB;                    // 20480 records per bin region

    // Workspace: emb | binned | spill | cnts | spill_cnt | spill_total |
    //            offdeg | bucket
    auto align256 = [](size_t x) { return (x + 255) & ~(size_t)255; };
    size_t o_emb    = 0;
    size_t o_binned = o_emb    + align256((size_t)n_nodes * D * sizeof(_Float16));
    size_t o_spill  = o_binned + align256((size_t)KB * nbins * CAPBB * 8);
    size_t o_cnts   = o_spill  + align256((size_t)KB * per_block * 8);
    size_t o_scnt   = o_cnts   + align256((size_t)KB * nbins * 4);
    size_t o_stot   = o_scnt   + align256((size_t)KB * 4);
    size_t o_offdeg = o_stot   + 256;
    size_t o_bucket = o_offdeg + align256((size_t)n_nodes * 8);
    size_t need     = o_bucket + align256((size_t)nbins * capb_out * 4);

    if (ws_size < need || nbins > NBMAX) {
        (void)hipMemsetAsync(d_out, 0, (size_t)out_size * sizeof(float), stream);
        long long total = (long long)n_edges * 32;
        edge_scatter_fallback<<<(int)((total + 255) / 256), 256, 0, stream>>>(
            ge, weight, e_feat, src, dst, out, n_edges);
        return;
    }

    char* ws = (char*)d_ws;
    _Float16*     emb     = (_Float16*)(ws + o_emb);
    uint2*        binned  = (uint2*)(ws + o_binned);
    uint2*        spill   = (uint2*)(ws + o_spill);
    int*          cnts    = (int*)(ws + o_cnts);
    int*          scnt    = (int*)(ws + o_scnt);
    int*          stot    = (int*)(ws + o_stot);
    uint2*        offdeg  = (uint2*)(ws + o_offdeg);
    unsigned int* bucket  = (unsigned int*)(ws + o_bucket);

    int quads = n_nodes * (D / 4);
    int embBlocks = (quads + NT - 1) / NT;

    fused_kernel<<<KB + embBlocks, NT, 0, stream>>>(
        ge, weight, e_feat, src, dst, emb, binned, cnts, spill, scnt,
        n_nodes, n_edges, nbins, per_block);
    csr_kernel<<<nbins, 1024, 0, stream>>>(binned, cnts, offdeg, bucket,
                                           scnt, stot, n_nodes, nbins, capb_out);

    long long total = (long long)n_nodes * 32;
    gather_kernel<<<(int)((total + 255) / 256), NT, 0, stream>>>(
        emb, offdeg, bucket, stot, scnt, spill, out, n_nodes, per_block);
}